// Round 2
// baseline (6627.038 us; speedup 1.0000x reference)
//
#include <hip/hip_runtime.h>
#include <hip/hip_bf16.h>
#include <math.h>

#define E_DIM 1024
#define NHEAD 16
#define HDIM 64
#define HID_DIM 2730
#define B_DIM 8
#define S_DIM 1025
#define EPS_V 1e-6f
#define SCALE_V 0.125f
#define MROWS (B_DIM * S_DIM)   // 8200

// ---------------- RMSNorm ----------------
__global__ __launch_bounds__(256) void rmsnorm_kernel(const float* __restrict__ x,
        const float* __restrict__ g, float* __restrict__ out) {
    int row = blockIdx.x;
    const float4* xr = (const float4*)(x + (size_t)row * E_DIM);
    float4 v = xr[threadIdx.x];                    // 256 threads * 4 = 1024
    float ss = v.x*v.x + v.y*v.y + v.z*v.z + v.w*v.w;
    #pragma unroll
    for (int off = 32; off > 0; off >>= 1) ss += __shfl_down(ss, off, 64);
    __shared__ float wsum[4];
    int lane = threadIdx.x & 63, w = threadIdx.x >> 6;
    if (lane == 0) wsum[w] = ss;
    __syncthreads();
    float tot = wsum[0] + wsum[1] + wsum[2] + wsum[3];
    float inv = rsqrtf(tot * (1.0f / E_DIM) + EPS_V);
    float4 gv = ((const float4*)g)[threadIdx.x];
    float4 o;
    o.x = v.x * inv * gv.x; o.y = v.y * inv * gv.y;
    o.z = v.z * inv * gv.z; o.w = v.w * inv * gv.w;
    ((float4*)(out + (size_t)row * E_DIM))[threadIdx.x] = o;
}

// ---------------- generic 64x64 SGEMM, C = A@B + bias (+R) ----------------
// A loads use float2 pairs (8B alignment suffices: fc2's A base is 8 mod 16).
template<bool RESID>
__global__ __launch_bounds__(256) void sgemm64(const float* __restrict__ A, int lda,
        const float* __restrict__ Bm, const float* __restrict__ bias,
        const float* __restrict__ R, float* __restrict__ C,
        int Mn, int Nn, int Kn) {
    __shared__ float As[16][68];   // k-major, padded
    __shared__ float Bs[16][64];
    int tid = threadIdx.x;
    int tx = tid & 15, ty = tid >> 4;
    int n0 = blockIdx.x * 64, m0 = blockIdx.y * 64;
    float acc[4][4] = {{0.f}};
    int arow = tid >> 2;          // 0..63
    int acol = (tid & 3) << 2;    // 0,4,8,12
    int brow = tid >> 4;          // 0..15
    int bcol = (tid & 15) << 2;   // 0..60

    for (int k0 = 0; k0 < Kn; k0 += 16) {
        int gm = m0 + arow;
        if (gm < Mn && (k0 + acol + 3) < Kn) {
            const float* ap = A + (size_t)gm * lda + k0 + acol;
            float2 a01 = *(const float2*)ap;
            float2 a23 = *(const float2*)(ap + 2);
            As[acol+0][arow] = a01.x; As[acol+1][arow] = a01.y;
            As[acol+2][arow] = a23.x; As[acol+3][arow] = a23.y;
        } else {
            #pragma unroll
            for (int e = 0; e < 4; e++) {
                int kk = k0 + acol + e;
                As[acol+e][arow] = (gm < Mn && kk < Kn) ? A[(size_t)gm * lda + kk] : 0.0f;
            }
        }
        int gk = k0 + brow;
        if (gk < Kn && (n0 + bcol + 3) < Nn) {
            *(float4*)&Bs[brow][bcol] = *(const float4*)(Bm + (size_t)gk * Nn + n0 + bcol);
        } else {
            #pragma unroll
            for (int e = 0; e < 4; e++) {
                int nn = n0 + bcol + e;
                Bs[brow][bcol+e] = (gk < Kn && nn < Nn) ? Bm[(size_t)gk * Nn + nn] : 0.0f;
            }
        }
        __syncthreads();
        #pragma unroll
        for (int kk = 0; kk < 16; kk++) {
            float4 a4 = *(const float4*)&As[kk][ty << 2];
            float4 b4 = *(const float4*)&Bs[kk][tx << 2];
            float a[4] = {a4.x, a4.y, a4.z, a4.w};
            float b[4] = {b4.x, b4.y, b4.z, b4.w};
            #pragma unroll
            for (int i = 0; i < 4; i++)
                #pragma unroll
                for (int j = 0; j < 4; j++)
                    acc[i][j] = fmaf(a[i], b[j], acc[i][j]);
        }
        __syncthreads();
    }
    #pragma unroll
    for (int i = 0; i < 4; i++) {
        int gm = m0 + (ty << 2) + i;
        if (gm >= Mn) continue;
        #pragma unroll
        for (int j = 0; j < 4; j++) {
            int gn = n0 + (tx << 2) + j;
            if (gn >= Nn) continue;
            float v = acc[i][j] + bias[gn];
            if (RESID) v += R[(size_t)gm * Nn + gn];
            C[(size_t)gm * Nn + gn] = v;
        }
    }
}

// ---------------- RoPE (per-batch, in-place on q,k of qkv_b) + q*SCALE ----------------
__global__ __launch_bounds__(256) void rope_kernel(float* __restrict__ qkvb) {
    int idx = blockIdx.x * 256 + threadIdx.x;   // over S*NH*32 = 524800
    int i = idx & 31;
    int h = (idx >> 5) & (NHEAD - 1);
    int s = idx >> 9;          // 0..1024
    float* q = qkvb + (size_t)s * 3072 + h * 64;
    float* k = q + 1024;
    if (s == 0) {              // task token: no rope, q still scaled
        q[i] *= SCALE_V;
        q[i + 32] *= SCALE_V;
        return;
    }
    float pos = (float)(s - 1);
    float invf = expf((float)i * (-9.210340371976184f / 32.0f)); // 10000^(-i/32)
    float f = pos * invf;
    float c = cosf(f), sn = sinf(f);
    float q1 = q[i], q2 = q[i + 32];
    q[i]      = (q1 * c - q2 * sn) * SCALE_V;
    q[i + 32] = (q2 * c + q1 * sn) * SCALE_V;
    float k1 = k[i], k2 = k[i + 32];
    k[i]      = k1 * c - k2 * sn;
    k[i + 32] = k2 * c + k1 * sn;
}

// ---------------- flash attention (per-batch, fp32, online softmax) ----------------
__global__ __launch_bounds__(256) void attn_kernel(const float* __restrict__ qkvb,
        float* __restrict__ attnb) {
    __shared__ float Qt[64][65];   // Q transposed: Qt[d][row]
    __shared__ float KP[64][65];   // K transposed (scores), then P transposed (PV)
    __shared__ float Vs[64][65];   // V: Vs[kpos][d]
    int qt = blockIdx.x, h = blockIdx.y;
    int tid = threadIdx.x;
    int tx = tid & 15, ty = tid >> 4;
    const float* qb = qkvb + h * 64;
    const float* kb = qb + 1024;
    const float* vb = qb + 2048;
    int lrow = tid >> 4;           // 0..15
    int lcol = (tid & 15) << 2;    // 0..60

    for (int r = lrow; r < 64; r += 16) {
        int s = qt * 64 + r;
        float4 v = make_float4(0.f, 0.f, 0.f, 0.f);
        if (s < S_DIM) v = *(const float4*)(qb + (size_t)s * 3072 + lcol);
        Qt[lcol+0][r] = v.x; Qt[lcol+1][r] = v.y;
        Qt[lcol+2][r] = v.z; Qt[lcol+3][r] = v.w;
    }
    float o[4][4] = {{0.f}};
    float mr[4], lr2[4];
    #pragma unroll
    for (int i = 0; i < 4; i++) { mr[i] = -1e30f; lr2[i] = 0.f; }

    for (int kt = 0; kt < 17; kt++) {
        __syncthreads();   // prev PV reads of KP/Vs done; Qt visible (first iter)
        for (int r = lrow; r < 64; r += 16) {
            int s = kt * 64 + r;
            float4 kv = make_float4(0,0,0,0), vv = make_float4(0,0,0,0);
            if (s < S_DIM) {
                kv = *(const float4*)(kb + (size_t)s * 3072 + lcol);
                vv = *(const float4*)(vb + (size_t)s * 3072 + lcol);
            }
            KP[lcol+0][r] = kv.x; KP[lcol+1][r] = kv.y;
            KP[lcol+2][r] = kv.z; KP[lcol+3][r] = kv.w;
            Vs[r][lcol+0] = vv.x; Vs[r][lcol+1] = vv.y;
            Vs[r][lcol+2] = vv.z; Vs[r][lcol+3] = vv.w;
        }
        __syncthreads();
        float sc[4][4] = {{0.f}};
        #pragma unroll 8
        for (int d = 0; d < 64; d++) {
            float qa[4], kk2[4];
            #pragma unroll
            for (int i = 0; i < 4; i++) qa[i] = Qt[d][(ty<<2)+i];
            #pragma unroll
            for (int j = 0; j < 4; j++) kk2[j] = KP[d][(tx<<2)+j];
            #pragma unroll
            for (int i = 0; i < 4; i++)
                #pragma unroll
                for (int j = 0; j < 4; j++)
                    sc[i][j] = fmaf(qa[i], kk2[j], sc[i][j]);
        }
        #pragma unroll
        for (int j = 0; j < 4; j++) {
            if (kt * 64 + (tx<<2) + j >= S_DIM) {
                #pragma unroll
                for (int i = 0; i < 4; i++) sc[i][j] = -1e30f;
            }
        }
        float al[4], pr[4][4], rs[4];
        #pragma unroll
        for (int i = 0; i < 4; i++) {
            float tm = fmaxf(fmaxf(sc[i][0], sc[i][1]), fmaxf(sc[i][2], sc[i][3]));
            #pragma unroll
            for (int off = 1; off < 16; off <<= 1)
                tm = fmaxf(tm, __shfl_xor(tm, off, 64));
            float mnew = fmaxf(mr[i], tm);
            al[i] = __expf(mr[i] - mnew);
            mr[i] = mnew;
            rs[i] = 0.f;
            #pragma unroll
            for (int j = 0; j < 4; j++) {
                pr[i][j] = __expf(sc[i][j] - mnew);
                rs[i] += pr[i][j];
            }
        }
        #pragma unroll
        for (int off = 1; off < 16; off <<= 1) {
            #pragma unroll
            for (int i = 0; i < 4; i++) rs[i] += __shfl_xor(rs[i], off, 64);
        }
        #pragma unroll
        for (int i = 0; i < 4; i++) {
            lr2[i] = lr2[i] * al[i] + rs[i];
            #pragma unroll
            for (int j = 0; j < 4; j++) o[i][j] *= al[i];
        }
        __syncthreads();   // all score reads of KP done before overwrite with P
        #pragma unroll
        for (int i = 0; i < 4; i++)
            #pragma unroll
            for (int j = 0; j < 4; j++)
                KP[(tx<<2)+j][(ty<<2)+i] = pr[i][j];   // P transposed: KP[c][row]
        __syncthreads();
        #pragma unroll 8
        for (int c = 0; c < 64; c++) {
            float pf[4], vf[4];
            #pragma unroll
            for (int i = 0; i < 4; i++) pf[i] = KP[c][(ty<<2)+i];
            #pragma unroll
            for (int j = 0; j < 4; j++) vf[j] = Vs[c][(tx<<2)+j];
            #pragma unroll
            for (int i = 0; i < 4; i++)
                #pragma unroll
                for (int j = 0; j < 4; j++)
                    o[i][j] = fmaf(pf[i], vf[j], o[i][j]);
        }
    }
    float* ob = attnb + h * 64;
    #pragma unroll
    for (int i = 0; i < 4; i++) {
        int s = qt * 64 + (ty<<2) + i;
        if (s >= S_DIM) continue;
        float invl = 1.0f / lr2[i];
        #pragma unroll
        for (int j = 0; j < 4; j++)
            ob[(size_t)s * E_DIM + (tx<<2) + j] = o[i][j] * invl;
    }
}

// ---------------- depthwise 3x3 conv + exact GELU + gate (per-batch) ----------------
// Writes the gated activation IN-PLACE into the vg half of hbuf_b (offset HID_DIM).
// Conv only reads the xg half (offsets < HID_DIM) of neighbor rows -> no hazard.
__global__ __launch_bounds__(256) void conv_gelu_kernel(float* __restrict__ hb,
        const float* __restrict__ dw_w, const float* __restrict__ dw_b) {
    int p = blockIdx.x;               // 0 = task token, 1.. = image pixels
    for (int c = threadIdx.x; c < HID_DIM; c += 256) {
        float val;
        if (p == 0) {
            val = hb[(size_t)p * 5460 + c];          // task: no conv, no dw_b
        } else {
            int pp = p - 1;
            int gy = pp >> 5, gx = pp & 31;
            float a = dw_b[c];
            #pragma unroll
            for (int dy = 0; dy < 3; dy++) {
                int ny = gy + dy - 1;
                if (ny < 0 || ny >= 32) continue;
                #pragma unroll
                for (int dx = 0; dx < 3; dx++) {
                    int nx = gx + dx - 1;
                    if (nx < 0 || nx >= 32) continue;
                    a = fmaf(hb[(size_t)(1 + ny * 32 + nx) * 5460 + c],
                             dw_w[(dy * 3 + dx) * HID_DIM + c], a);
                }
            }
            val = a;
        }
        float ge = 0.5f * val * (1.0f + erff(val * 0.70710678118654752f));
        hb[(size_t)p * 5460 + HID_DIM + c] = ge * hb[(size_t)p * 5460 + HID_DIM + c];
    }
}

// ---------------- launch ----------------
extern "C" void kernel_launch(void* const* d_in, const int* in_sizes, int n_in,
                              void* d_out, int out_size, void* d_ws, size_t ws_size,
                              hipStream_t stream) {
    const float* x      = (const float*)d_in[0];
    const float* g1     = (const float*)d_in[1];
    const float* w_qkv  = (const float*)d_in[2];
    const float* b_qkv  = (const float*)d_in[3];
    const float* w_proj = (const float*)d_in[4];
    const float* b_proj = (const float*)d_in[5];
    const float* g2     = (const float*)d_in[6];
    const float* fc1_w  = (const float*)d_in[7];
    const float* fc1_b  = (const float*)d_in[8];
    const float* dw_w   = (const float*)d_in[9];
    const float* dw_b   = (const float*)d_in[10];
    const float* fc2_w  = (const float*)d_in[11];
    const float* fc2_b  = (const float*)d_in[12];
    float* out = (float*)d_out;
    float* ws  = (float*)d_ws;

    // ws layout (floats), peak usage ~56 MB:
    float* xn    = ws;                 // 8,396,800  (33.6 MB) xn / xn2
    float* qkvb  = ws + 8396800;       // 3,148,800  (12.6 MB) per-batch qkv
    float* attnb = ws + 11545600;      // 1,049,600  ( 4.2 MB) per-batch attn out
    float* hbufb = ws + 8396800;       // 5,596,500  (22.4 MB) per-batch fc1 out (reuses qkv region)
    // total: 13,993,300 floats = 56.0 MB

    // ---- attention block ----
    rmsnorm_kernel<<<MROWS, 256, 0, stream>>>(x, g1, xn);
    for (int b = 0; b < B_DIM; b++) {
        const float* xnb = xn + (size_t)b * S_DIM * E_DIM;
        const float* xb  = x  + (size_t)b * S_DIM * E_DIM;
        float* outb      = out + (size_t)b * S_DIM * E_DIM;
        sgemm64<false><<<dim3(48, 17), 256, 0, stream>>>(xnb, 1024, w_qkv, b_qkv, nullptr, qkvb, S_DIM, 3072, 1024);
        rope_kernel<<<(S_DIM * NHEAD * 32) / 256, 256, 0, stream>>>(qkvb);
        attn_kernel<<<dim3(17, NHEAD), 256, 0, stream>>>(qkvb, attnb);
        sgemm64<true><<<dim3(16, 17), 256, 0, stream>>>(attnb, 1024, w_proj, b_proj, xb, outb, S_DIM, 1024, 1024);
    }

    // ---- MLP block ----
    rmsnorm_kernel<<<MROWS, 256, 0, stream>>>(out, g2, xn);
    for (int b = 0; b < B_DIM; b++) {
        const float* xnb = xn + (size_t)b * S_DIM * E_DIM;
        float* outb      = out + (size_t)b * S_DIM * E_DIM;
        sgemm64<false><<<dim3(86, 17), 256, 0, stream>>>(xnb, 1024, fc1_w, fc1_b, nullptr, hbufb, S_DIM, 5460, 1024);
        conv_gelu_kernel<<<S_DIM, 256, 0, stream>>>(hbufb, dw_w, dw_b);
        sgemm64<true><<<dim3(16, 17), 256, 0, stream>>>(hbufb + HID_DIM, 5460, fc2_w, fc2_b, outb, outb, S_DIM, 1024, HID_DIM);
    }
}

// Round 3
// 3641.853 us; speedup vs baseline: 1.8197x; 1.8197x over previous
//
#include <hip/hip_runtime.h>
#include <hip/hip_bf16.h>
#include <math.h>

#define E_DIM 1024
#define NHEAD 16
#define HID_DIM 2730
#define KP_FC2 2752
#define B_DIM 8
#define S_DIM 1025
#define EPS_V 1e-6f
#define SCALE_V 0.125f
#define MROWS (B_DIM * S_DIM)   // 8200

typedef __attribute__((ext_vector_type(8))) short short8;
typedef __attribute__((ext_vector_type(4))) float f32x4;

__device__ __forceinline__ float b2f(unsigned short u) {
    union { unsigned int i; float f; } x; x.i = ((unsigned int)u) << 16; return x.f;
}
__device__ __forceinline__ unsigned short f2b(float f) {
    __hip_bfloat16 h = __float2bfloat16(f);
    return *reinterpret_cast<unsigned short*>(&h);
}

__device__ __forceinline__ void stage16(const void* g, void* l) {
    __builtin_amdgcn_global_load_lds(
        (const __attribute__((address_space(1))) unsigned int*)g,
        (__attribute__((address_space(3))) unsigned int*)l,
        16, 0, 0);
}

// ---------------- RMSNorm (fp32 in -> bf16 out) ----------------
__global__ __launch_bounds__(256) void rmsnorm_kernel(const float* __restrict__ x,
        const float* __restrict__ g, unsigned short* __restrict__ out) {
    int row = blockIdx.x;
    const float4* xr = (const float4*)(x + (size_t)row * E_DIM);
    float4 v = xr[threadIdx.x];
    float ss = v.x*v.x + v.y*v.y + v.z*v.z + v.w*v.w;
    #pragma unroll
    for (int off = 32; off > 0; off >>= 1) ss += __shfl_down(ss, off, 64);
    __shared__ float wsum[4];
    int lane = threadIdx.x & 63, w = threadIdx.x >> 6;
    if (lane == 0) wsum[w] = ss;
    __syncthreads();
    float tot = wsum[0] + wsum[1] + wsum[2] + wsum[3];
    float inv = rsqrtf(tot * (1.0f / E_DIM) + EPS_V);
    float4 gv = ((const float4*)g)[threadIdx.x];
    ushort4 o;
    o.x = f2b(v.x * inv * gv.x); o.y = f2b(v.y * inv * gv.y);
    o.z = f2b(v.z * inv * gv.z); o.w = f2b(v.w * inv * gv.w);
    ((ushort4*)(out + (size_t)row * E_DIM))[threadIdx.x] = o;
}

// ---------------- weight convert+transpose: W[K][N] f32 -> WT[n][k] bf16, k padded to KP (zeros) ----------------
__global__ __launch_bounds__(256) void convt_kernel(const float* __restrict__ W,
        unsigned short* __restrict__ WT, int K, int N, int KPad) {
    __shared__ float T[32][33];
    int n0 = blockIdx.x * 32, k0 = blockIdx.y * 32;
    int c = threadIdx.x & 31, r4 = (threadIdx.x >> 5) << 2;
    #pragma unroll
    for (int i = 0; i < 4; i++) {
        int k = k0 + r4 + i, n = n0 + c;
        T[c][r4 + i] = (k < K && n < N) ? W[(size_t)k * N + n] : 0.0f;
    }
    __syncthreads();
    #pragma unroll
    for (int i = 0; i < 4; i++) {
        int n = n0 + r4 + i, k = k0 + c;
        if (n < N && k < KPad) WT[(size_t)n * KPad + k] = f2b(T[r4 + i][c]);
    }
}

// ---------------- bf16 MFMA GEMM: C = A @ WT^T + bias (+R) ----------------
// A: [M][K] bf16 (row stride K), WT: [N][K] bf16 (row stride K), K % 32 == 0.
// A and WT buffers must be readable up to 128-row tile boundaries.
// BF16OUT: C bf16 [ldc], else C fp32 [ldc] with residual R added.
template<bool BF16OUT>
__global__ __launch_bounds__(256) void gemm_mfma(const unsigned short* __restrict__ A,
        const unsigned short* __restrict__ Bt, const float* __restrict__ bias,
        const float* __restrict__ R, void* __restrict__ Cv,
        int M, int N, int K, int ldc) {
    __shared__ __align__(16) unsigned short ldsA[4096];   // [kc 0..3][row 0..127] x 8 bf16
    __shared__ __align__(16) unsigned short ldsB[4096];
    int tid = threadIdx.x;
    int lane = tid & 63;
    int w = tid >> 6;                 // wave 0..3
    int wm = w >> 1, wn = w & 1;
    int m0 = blockIdx.y * 128, n0 = blockIdx.x * 128;

    // staging: wave w loads chunks c0=2w, c1=2w+1 for both A and B
    int c0 = 2 * w, c1 = 2 * w + 1;
    int kc0 = c0 & 3, rh0 = (c0 >> 2) * 64;
    int kc1 = c1 & 3, rh1 = (c1 >> 2) * 64;
    const unsigned short* gA0 = A + (size_t)(m0 + rh0 + lane) * K + kc0 * 8;
    const unsigned short* gA1 = A + (size_t)(m0 + rh1 + lane) * K + kc1 * 8;
    const unsigned short* gB0 = Bt + (size_t)(n0 + rh0 + lane) * K + kc0 * 8;
    const unsigned short* gB1 = Bt + (size_t)(n0 + rh1 + lane) * K + kc1 * 8;
    unsigned short* lA0 = ldsA + (kc0 * 128 + rh0) * 8;
    unsigned short* lA1 = ldsA + (kc1 * 128 + rh1) * 8;
    unsigned short* lB0 = ldsB + (kc0 * 128 + rh0) * 8;
    unsigned short* lB1 = ldsB + (kc1 * 128 + rh1) * 8;

    f32x4 acc[4][4];
    #pragma unroll
    for (int i = 0; i < 4; i++)
        #pragma unroll
        for (int j = 0; j < 4; j++) acc[i][j] = (f32x4){0.f, 0.f, 0.f, 0.f};

    const unsigned short* pa = ldsA + ((lane >> 4) * 128 + wm * 64 + (lane & 15)) * 8;
    const unsigned short* pb = ldsB + ((lane >> 4) * 128 + wn * 64 + (lane & 15)) * 8;

    for (int k0 = 0; k0 < K; k0 += 32) {
        stage16(gA0 + k0, lA0);
        stage16(gA1 + k0, lA1);
        stage16(gB0 + k0, lB0);
        stage16(gB1 + k0, lB1);
        __syncthreads();
        short8 af[4], bfr[4];
        #pragma unroll
        for (int i = 0; i < 4; i++) af[i] = *(const short8*)(pa + i * 128);
        #pragma unroll
        for (int j = 0; j < 4; j++) bfr[j] = *(const short8*)(pb + j * 128);
        #pragma unroll
        for (int i = 0; i < 4; i++)
            #pragma unroll
            for (int j = 0; j < 4; j++)
                acc[i][j] = __builtin_amdgcn_mfma_f32_16x16x32_bf16(af[i], bfr[j], acc[i][j], 0, 0, 0);
        __syncthreads();
    }

    int cr = (lane >> 4) * 4;      // C/D: row = (lane>>4)*4 + reg, col = lane&15
    int cc = lane & 15;
    #pragma unroll
    for (int i = 0; i < 4; i++) {
        int gmb = m0 + wm * 64 + i * 16 + cr;
        #pragma unroll
        for (int j = 0; j < 4; j++) {
            int gn = n0 + wn * 64 + j * 16 + cc;
            if (gn >= N) continue;
            float bs = bias[gn];
            #pragma unroll
            for (int r = 0; r < 4; r++) {
                int gm = gmb + r;
                if (gm >= M) continue;
                float v = acc[i][j][r] + bs;
                if (BF16OUT) {
                    ((unsigned short*)Cv)[(size_t)gm * ldc + gn] = f2b(v);
                } else {
                    ((float*)Cv)[(size_t)gm * ldc + gn] = v + R[(size_t)gm * ldc + gn];
                }
            }
        }
    }
}

// ---------------- RoPE (per-batch, in-place on bf16 qkv) + q*SCALE ----------------
__global__ __launch_bounds__(256) void rope_kernel(unsigned short* __restrict__ qkvb) {
    int idx = blockIdx.x * 256 + threadIdx.x;   // over S*NH*32 = 524800
    int i = idx & 31;
    int h = (idx >> 5) & (NHEAD - 1);
    int s = idx >> 9;          // 0..1024
    unsigned short* q = qkvb + (size_t)s * 3072 + h * 64;
    unsigned short* k = q + 1024;
    if (s == 0) {
        q[i] = f2b(b2f(q[i]) * SCALE_V);
        q[i + 32] = f2b(b2f(q[i + 32]) * SCALE_V);
        return;
    }
    float pos = (float)(s - 1);
    float invf = expf((float)i * (-9.210340371976184f / 32.0f));
    float f = pos * invf;
    float c = cosf(f), sn = sinf(f);
    float q1 = b2f(q[i]), q2 = b2f(q[i + 32]);
    q[i]      = f2b((q1 * c - q2 * sn) * SCALE_V);
    q[i + 32] = f2b((q2 * c + q1 * sn) * SCALE_V);
    float k1 = b2f(k[i]), k2 = b2f(k[i + 32]);
    k[i]      = f2b(k1 * c - k2 * sn);
    k[i + 32] = f2b(k2 * c + k1 * sn);
}

// ---------------- flash attention (per-batch, bf16 in/out, fp32 math) ----------------
__global__ __launch_bounds__(256) void attn_kernel(const unsigned short* __restrict__ qkvb,
        unsigned short* __restrict__ attnb) {
    __shared__ float Qt[64][65];
    __shared__ float KP[64][65];
    __shared__ float Vs[64][65];
    int qt = blockIdx.x, h = blockIdx.y;
    int tid = threadIdx.x;
    int tx = tid & 15, ty = tid >> 4;
    const unsigned short* qb = qkvb + h * 64;
    const unsigned short* kb = qb + 1024;
    const unsigned short* vb = qb + 2048;
    int lrow = tid >> 4;
    int lcol = (tid & 15) << 2;

    for (int r = lrow; r < 64; r += 16) {
        int s = qt * 64 + r;
        float4 v = make_float4(0.f, 0.f, 0.f, 0.f);
        if (s < S_DIM) {
            ushort4 u = *(const ushort4*)(qb + (size_t)s * 3072 + lcol);
            v = make_float4(b2f(u.x), b2f(u.y), b2f(u.z), b2f(u.w));
        }
        Qt[lcol+0][r] = v.x; Qt[lcol+1][r] = v.y;
        Qt[lcol+2][r] = v.z; Qt[lcol+3][r] = v.w;
    }
    float o[4][4] = {{0.f}};
    float mr[4], lr2[4];
    #pragma unroll
    for (int i = 0; i < 4; i++) { mr[i] = -1e30f; lr2[i] = 0.f; }

    for (int kt = 0; kt < 17; kt++) {
        __syncthreads();
        for (int r = lrow; r < 64; r += 16) {
            int s = kt * 64 + r;
            float4 kv = make_float4(0,0,0,0), vv = make_float4(0,0,0,0);
            if (s < S_DIM) {
                ushort4 ku = *(const ushort4*)(kb + (size_t)s * 3072 + lcol);
                ushort4 vu = *(const ushort4*)(vb + (size_t)s * 3072 + lcol);
                kv = make_float4(b2f(ku.x), b2f(ku.y), b2f(ku.z), b2f(ku.w));
                vv = make_float4(b2f(vu.x), b2f(vu.y), b2f(vu.z), b2f(vu.w));
            }
            KP[lcol+0][r] = kv.x; KP[lcol+1][r] = kv.y;
            KP[lcol+2][r] = kv.z; KP[lcol+3][r] = kv.w;
            Vs[r][lcol+0] = vv.x; Vs[r][lcol+1] = vv.y;
            Vs[r][lcol+2] = vv.z; Vs[r][lcol+3] = vv.w;
        }
        __syncthreads();
        float sc[4][4] = {{0.f}};
        #pragma unroll 8
        for (int d = 0; d < 64; d++) {
            float qa[4], kk2[4];
            #pragma unroll
            for (int i = 0; i < 4; i++) qa[i] = Qt[d][(ty<<2)+i];
            #pragma unroll
            for (int j = 0; j < 4; j++) kk2[j] = KP[d][(tx<<2)+j];
            #pragma unroll
            for (int i = 0; i < 4; i++)
                #pragma unroll
                for (int j = 0; j < 4; j++)
                    sc[i][j] = fmaf(qa[i], kk2[j], sc[i][j]);
        }
        #pragma unroll
        for (int j = 0; j < 4; j++) {
            if (kt * 64 + (tx<<2) + j >= S_DIM) {
                #pragma unroll
                for (int i = 0; i < 4; i++) sc[i][j] = -1e30f;
            }
        }
        float al[4], pr[4][4], rs[4];
        #pragma unroll
        for (int i = 0; i < 4; i++) {
            float tm = fmaxf(fmaxf(sc[i][0], sc[i][1]), fmaxf(sc[i][2], sc[i][3]));
            #pragma unroll
            for (int off = 1; off < 16; off <<= 1)
                tm = fmaxf(tm, __shfl_xor(tm, off, 64));
            float mnew = fmaxf(mr[i], tm);
            al[i] = __expf(mr[i] - mnew);
            mr[i] = mnew;
            rs[i] = 0.f;
            #pragma unroll
            for (int j = 0; j < 4; j++) {
                pr[i][j] = __expf(sc[i][j] - mnew);
                rs[i] += pr[i][j];
            }
        }
        #pragma unroll
        for (int off = 1; off < 16; off <<= 1) {
            #pragma unroll
            for (int i = 0; i < 4; i++) rs[i] += __shfl_xor(rs[i], off, 64);
        }
        #pragma unroll
        for (int i = 0; i < 4; i++) {
            lr2[i] = lr2[i] * al[i] + rs[i];
            #pragma unroll
            for (int j = 0; j < 4; j++) o[i][j] *= al[i];
        }
        __syncthreads();
        #pragma unroll
        for (int i = 0; i < 4; i++)
            #pragma unroll
            for (int j = 0; j < 4; j++)
                KP[(tx<<2)+j][(ty<<2)+i] = pr[i][j];
        __syncthreads();
        #pragma unroll 8
        for (int c = 0; c < 64; c++) {
            float pf[4], vf[4];
            #pragma unroll
            for (int i = 0; i < 4; i++) pf[i] = KP[c][(ty<<2)+i];
            #pragma unroll
            for (int j = 0; j < 4; j++) vf[j] = Vs[c][(tx<<2)+j];
            #pragma unroll
            for (int i = 0; i < 4; i++)
                #pragma unroll
                for (int j = 0; j < 4; j++)
                    o[i][j] = fmaf(pf[i], vf[j], o[i][j]);
        }
    }
    unsigned short* ob = attnb + h * 64;
    #pragma unroll
    for (int i = 0; i < 4; i++) {
        int s = qt * 64 + (ty<<2) + i;
        if (s >= S_DIM) continue;
        float invl = 1.0f / lr2[i];
        #pragma unroll
        for (int j = 0; j < 4; j++)
            ob[(size_t)s * E_DIM + (tx<<2) + j] = f2b(o[i][j] * invl);
    }
}

// ---------------- depthwise 3x3 conv + exact GELU + gate (per-batch, bf16) ----------------
// hb: [1025][5460] bf16 (xg | vg). act: [1152][KP_FC2] bf16, cols [2730,2752) zeroed.
__global__ __launch_bounds__(256) void conv_gelu_kernel(const unsigned short* __restrict__ hb,
        const float* __restrict__ dw_w, const float* __restrict__ dw_b,
        unsigned short* __restrict__ act) {
    int p = blockIdx.x;               // 0 = task token, 1.. = image pixels
    for (int c = threadIdx.x; c < KP_FC2; c += 256) {
        if (c >= HID_DIM) { act[(size_t)p * KP_FC2 + c] = 0; continue; }
        float val;
        if (p == 0) {
            val = b2f(hb[(size_t)p * 5460 + c]);
        } else {
            int pp = p - 1;
            int gy = pp >> 5, gx = pp & 31;
            float a = dw_b[c];
            #pragma unroll
            for (int dy = 0; dy < 3; dy++) {
                int ny = gy + dy - 1;
                if (ny < 0 || ny >= 32) continue;
                #pragma unroll
                for (int dx = 0; dx < 3; dx++) {
                    int nx = gx + dx - 1;
                    if (nx < 0 || nx >= 32) continue;
                    a = fmaf(b2f(hb[(size_t)(1 + ny * 32 + nx) * 5460 + c]),
                             dw_w[(dy * 3 + dx) * HID_DIM + c], a);
                }
            }
            val = a;
        }
        float ge = 0.5f * val * (1.0f + erff(val * 0.70710678118654752f));
        act[(size_t)p * KP_FC2 + c] = f2b(ge * b2f(hb[(size_t)p * 5460 + HID_DIM + c]));
    }
}

// ---------------- launch ----------------
extern "C" void kernel_launch(void* const* d_in, const int* in_sizes, int n_in,
                              void* d_out, int out_size, void* d_ws, size_t ws_size,
                              hipStream_t stream) {
    const float* x      = (const float*)d_in[0];
    const float* g1     = (const float*)d_in[1];
    const float* w_qkv  = (const float*)d_in[2];
    const float* b_qkv  = (const float*)d_in[3];
    const float* w_proj = (const float*)d_in[4];
    const float* b_proj = (const float*)d_in[5];
    const float* g2     = (const float*)d_in[6];
    const float* fc1_w  = (const float*)d_in[7];
    const float* fc1_b  = (const float*)d_in[8];
    const float* dw_w   = (const float*)d_in[9];
    const float* dw_b   = (const float*)d_in[10];
    const float* fc2_w  = (const float*)d_in[11];
    const float* fc2_b  = (const float*)d_in[12];
    float* out = (float*)d_out;
    char* base = (char*)d_ws;

    // byte offsets; peak ws ~51.7 MB (< proven-safe 56 MB)
    unsigned short* xn    = (unsigned short*)(base + 0);          // 8448 x 1024 bf16 (tile-pad rows)
    unsigned short* attnb = (unsigned short*)(base + 17301504);   // 8320 x 1024 bf16
    unsigned short* hbufb = (unsigned short*)(base + 17301504);   // phase2: 1025 x 5460 bf16
    unsigned short* actb  = (unsigned short*)(base + 28494592);   // phase2: 1152 x 2752 bf16
    unsigned short* wT1   = (unsigned short*)(base + 34835200);   // qkvT(6.3M) / projT / fc1T(11.3M)
    unsigned short* qkvb  = (unsigned short*)(base + 41126656);   // phase1: 1025 x 3072 bf16
    unsigned short* wT2   = (unsigned short*)(base + 46107392);   // phase2: fc2T 1024 x 2752 bf16

    // ---- attention block ----
    rmsnorm_kernel<<<MROWS, 256, 0, stream>>>(x, g1, xn);
    convt_kernel<<<dim3(96, 32), 256, 0, stream>>>(w_qkv, wT1, 1024, 3072, 1024);
    for (int b = 0; b < B_DIM; b++) {
        const unsigned short* xnb = xn + (size_t)b * S_DIM * E_DIM;
        gemm_mfma<true><<<dim3(24, 9), 256, 0, stream>>>(xnb, wT1, b_qkv, nullptr,
                qkvb, S_DIM, 3072, 1024, 3072);
        rope_kernel<<<(S_DIM * NHEAD * 32) / 256, 256, 0, stream>>>(qkvb);
        attn_kernel<<<dim3(17, NHEAD), 256, 0, stream>>>(qkvb, attnb + (size_t)b * S_DIM * E_DIM);
    }
    convt_kernel<<<dim3(32, 32), 256, 0, stream>>>(w_proj, wT1, 1024, 1024, 1024);
    gemm_mfma<false><<<dim3(8, 65), 256, 0, stream>>>(attnb, wT1, b_proj, x,
            out, MROWS, 1024, 1024, 1024);

    // ---- MLP block ----
    rmsnorm_kernel<<<MROWS, 256, 0, stream>>>(out, g2, xn);
    convt_kernel<<<dim3(171, 32), 256, 0, stream>>>(fc1_w, wT1, 1024, 5460, 1024);
    convt_kernel<<<dim3(32, 86), 256, 0, stream>>>(fc2_w, wT2, HID_DIM, 1024, KP_FC2);
    for (int b = 0; b < B_DIM; b++) {
        const unsigned short* xnb = xn + (size_t)b * S_DIM * E_DIM;
        float* outb = out + (size_t)b * S_DIM * E_DIM;
        gemm_mfma<true><<<dim3(43, 9), 256, 0, stream>>>(xnb, wT1, fc1_b, nullptr,
                hbufb, S_DIM, 5460, 1024, 5460);
        conv_gelu_kernel<<<S_DIM, 256, 0, stream>>>(hbufb, dw_w, dw_b, actb);
        gemm_mfma<false><<<dim3(8, 9), 256, 0, stream>>>(actb, wT2, fc2_b, outb,
                outb, S_DIM, 1024, KP_FC2, 1024);
    }
}

// Round 4
// 2192.406 us; speedup vs baseline: 3.0227x; 1.6611x over previous
//
#include <hip/hip_runtime.h>
#include <hip/hip_bf16.h>
#include <math.h>

#define E_DIM 1024
#define NHEAD 16
#define HID_DIM 2730
#define KP_FC2 2752
#define B_DIM 8
#define S_DIM 1025
#define EPS_V 1e-6f
#define SCALE_V 0.125f
#define MROWS (B_DIM * S_DIM)   // 8200

typedef __attribute__((ext_vector_type(8))) short short8;
typedef __attribute__((ext_vector_type(4))) float f32x4;

__device__ __forceinline__ float b2f(unsigned short u) {
    union { unsigned int i; float f; } x; x.i = ((unsigned int)u) << 16; return x.f;
}
__device__ __forceinline__ unsigned short f2b(float f) {
    __hip_bfloat16 h = __float2bfloat16(f);
    return *reinterpret_cast<unsigned short*>(&h);
}

__device__ __forceinline__ void stage16(const void* g, void* l) {
    __builtin_amdgcn_global_load_lds(
        (const __attribute__((address_space(1))) unsigned int*)g,
        (__attribute__((address_space(3))) unsigned int*)l,
        16, 0, 0);
}

// u16 index of the 8-element group at (row, c8) in a XOR-swizzled [64][64] bf16 tile
__device__ __forceinline__ int sl(int row, int c8) {
    return (row * 8 + (c8 ^ (row & 7))) * 8;
}

// ---------------- RMSNorm (fp32 in -> bf16 out) ----------------
__global__ __launch_bounds__(256) void rmsnorm_kernel(const float* __restrict__ x,
        const float* __restrict__ g, unsigned short* __restrict__ out) {
    int row = blockIdx.x;
    const float4* xr = (const float4*)(x + (size_t)row * E_DIM);
    float4 v = xr[threadIdx.x];
    float ss = v.x*v.x + v.y*v.y + v.z*v.z + v.w*v.w;
    #pragma unroll
    for (int off = 32; off > 0; off >>= 1) ss += __shfl_down(ss, off, 64);
    __shared__ float wsum[4];
    int lane = threadIdx.x & 63, w = threadIdx.x >> 6;
    if (lane == 0) wsum[w] = ss;
    __syncthreads();
    float tot = wsum[0] + wsum[1] + wsum[2] + wsum[3];
    float inv = rsqrtf(tot * (1.0f / E_DIM) + EPS_V);
    float4 gv = ((const float4*)g)[threadIdx.x];
    ushort4 o;
    o.x = f2b(v.x * inv * gv.x); o.y = f2b(v.y * inv * gv.y);
    o.z = f2b(v.z * inv * gv.z); o.w = f2b(v.w * inv * gv.w);
    ((ushort4*)(out + (size_t)row * E_DIM))[threadIdx.x] = o;
}

// ---------------- weight convert+transpose: W[K][N] f32 -> WT[n][k] bf16 ----------------
__global__ __launch_bounds__(256) void convt_kernel(const float* __restrict__ W,
        unsigned short* __restrict__ WT, int K, int N, int KPad) {
    __shared__ float T[32][33];
    int n0 = blockIdx.x * 32, k0 = blockIdx.y * 32;
    int c = threadIdx.x & 31, r4 = (threadIdx.x >> 5) << 2;
    #pragma unroll
    for (int i = 0; i < 4; i++) {
        int k = k0 + r4 + i, n = n0 + c;
        T[c][r4 + i] = (k < K && n < N) ? W[(size_t)k * N + n] : 0.0f;
    }
    __syncthreads();
    #pragma unroll
    for (int i = 0; i < 4; i++) {
        int n = n0 + r4 + i, k = k0 + c;
        if (n < N && k < KPad) WT[(size_t)n * KPad + k] = f2b(T[r4 + i][c]);
    }
}

// ---------------- bf16 MFMA GEMM (unchanged, proven) ----------------
template<bool BF16OUT>
__global__ __launch_bounds__(256) void gemm_mfma(const unsigned short* __restrict__ A,
        const unsigned short* __restrict__ Bt, const float* __restrict__ bias,
        const float* __restrict__ R, void* __restrict__ Cv,
        int M, int N, int K, int ldc) {
    __shared__ __align__(16) unsigned short ldsA[4096];
    __shared__ __align__(16) unsigned short ldsB[4096];
    int tid = threadIdx.x;
    int lane = tid & 63;
    int w = tid >> 6;
    int wm = w >> 1, wn = w & 1;
    int m0 = blockIdx.y * 128, n0 = blockIdx.x * 128;

    int c0 = 2 * w, c1 = 2 * w + 1;
    int kc0 = c0 & 3, rh0 = (c0 >> 2) * 64;
    int kc1 = c1 & 3, rh1 = (c1 >> 2) * 64;
    const unsigned short* gA0 = A + (size_t)(m0 + rh0 + lane) * K + kc0 * 8;
    const unsigned short* gA1 = A + (size_t)(m0 + rh1 + lane) * K + kc1 * 8;
    const unsigned short* gB0 = Bt + (size_t)(n0 + rh0 + lane) * K + kc0 * 8;
    const unsigned short* gB1 = Bt + (size_t)(n0 + rh1 + lane) * K + kc1 * 8;
    unsigned short* lA0 = ldsA + (kc0 * 128 + rh0) * 8;
    unsigned short* lA1 = ldsA + (kc1 * 128 + rh1) * 8;
    unsigned short* lB0 = ldsB + (kc0 * 128 + rh0) * 8;
    unsigned short* lB1 = ldsB + (kc1 * 128 + rh1) * 8;

    f32x4 acc[4][4];
    #pragma unroll
    for (int i = 0; i < 4; i++)
        #pragma unroll
        for (int j = 0; j < 4; j++) acc[i][j] = (f32x4){0.f, 0.f, 0.f, 0.f};

    const unsigned short* pa = ldsA + ((lane >> 4) * 128 + wm * 64 + (lane & 15)) * 8;
    const unsigned short* pb = ldsB + ((lane >> 4) * 128 + wn * 64 + (lane & 15)) * 8;

    for (int k0 = 0; k0 < K; k0 += 32) {
        stage16(gA0 + k0, lA0);
        stage16(gA1 + k0, lA1);
        stage16(gB0 + k0, lB0);
        stage16(gB1 + k0, lB1);
        __syncthreads();
        short8 af[4], bfr[4];
        #pragma unroll
        for (int i = 0; i < 4; i++) af[i] = *(const short8*)(pa + i * 128);
        #pragma unroll
        for (int j = 0; j < 4; j++) bfr[j] = *(const short8*)(pb + j * 128);
        #pragma unroll
        for (int i = 0; i < 4; i++)
            #pragma unroll
            for (int j = 0; j < 4; j++)
                acc[i][j] = __builtin_amdgcn_mfma_f32_16x16x32_bf16(af[i], bfr[j], acc[i][j], 0, 0, 0);
        __syncthreads();
    }

    int cr = (lane >> 4) * 4;
    int cc = lane & 15;
    #pragma unroll
    for (int i = 0; i < 4; i++) {
        int gmb = m0 + wm * 64 + i * 16 + cr;
        #pragma unroll
        for (int j = 0; j < 4; j++) {
            int gn = n0 + wn * 64 + j * 16 + cc;
            if (gn >= N) continue;
            float bs = bias[gn];
            #pragma unroll
            for (int r = 0; r < 4; r++) {
                int gm = gmb + r;
                if (gm >= M) continue;
                float v = acc[i][j][r] + bs;
                if (BF16OUT) {
                    ((unsigned short*)Cv)[(size_t)gm * ldc + gn] = f2b(v);
                } else {
                    ((float*)Cv)[(size_t)gm * ldc + gn] = v + R[(size_t)gm * ldc + gn];
                }
            }
        }
    }
}

// ---------------- RoPE (per 2-batch chunk, in-place, rows 0..2049) ----------------
__global__ __launch_bounds__(256) void rope_kernel(unsigned short* __restrict__ qkv2) {
    int idx = blockIdx.x * 256 + threadIdx.x;   // over 2*1025*16*32 = 1,049,600
    int i = idx & 31;
    int h = (idx >> 5) & (NHEAD - 1);
    int rc = idx >> 9;          // 0..2049 (row in chunk)
    int s = (rc < S_DIM) ? rc : rc - S_DIM;
    unsigned short* q = qkv2 + (size_t)rc * 3072 + h * 64;
    unsigned short* k = q + 1024;
    if (s == 0) {
        q[i] = f2b(b2f(q[i]) * SCALE_V);
        q[i + 32] = f2b(b2f(q[i + 32]) * SCALE_V);
        return;
    }
    float pos = (float)(s - 1);
    float invf = expf((float)i * (-9.210340371976184f / 32.0f));
    float f = pos * invf;
    float c = cosf(f), sn = sinf(f);
    float q1 = b2f(q[i]), q2 = b2f(q[i + 32]);
    q[i]      = f2b((q1 * c - q2 * sn) * SCALE_V);
    q[i + 32] = f2b((q2 * c + q1 * sn) * SCALE_V);
    float k1 = b2f(k[i]), k2 = b2f(k[i + 32]);
    k[i]      = f2b(k1 * c - k2 * sn);
    k[i + 32] = f2b(k2 * c + k1 * sn);
}

// ---------------- V transpose: qkv2 v-section -> Vt[bc][h][d][1088] (zero-pad s>=1025) ----------------
__global__ __launch_bounds__(256) void vtrans_kernel(const unsigned short* __restrict__ qkv2,
        unsigned short* __restrict__ Vt) {
    __shared__ unsigned short T[64][65];
    int st = blockIdx.x, h = blockIdx.y, bc = blockIdx.z;
    int tid = threadIdx.x;
    int r = tid & 63, cb = (tid >> 6) * 16;
    const unsigned short* src = qkv2 + (size_t)(bc * S_DIM + st * 64 + r) * 3072 + 2048 + h * 64 + cb;
    #pragma unroll
    for (int i = 0; i < 4; i++) {
        ushort4 v = *(const ushort4*)(src + i * 4);
        T[cb + i*4 + 0][r] = v.x; T[cb + i*4 + 1][r] = v.y;
        T[cb + i*4 + 2][r] = v.z; T[cb + i*4 + 3][r] = v.w;
    }
    __syncthreads();
    int d = tid >> 2, sc = (tid & 3) * 16;
    unsigned short* dst = Vt + ((size_t)((bc * 16 + h) * 64 + d)) * 1088 + st * 64 + sc;
    #pragma unroll
    for (int g = 0; g < 4; g++) {
        ushort4 o;
        int i0 = sc + g * 4;
        o.x = (st*64 + i0 + 0 < S_DIM) ? T[d][i0 + 0] : 0;
        o.y = (st*64 + i0 + 1 < S_DIM) ? T[d][i0 + 1] : 0;
        o.z = (st*64 + i0 + 2 < S_DIM) ? T[d][i0 + 2] : 0;
        o.w = (st*64 + i0 + 3 < S_DIM) ? T[d][i0 + 3] : 0;
        *(ushort4*)(dst + g * 4) = o;
    }
}

// ---------------- MFMA flash attention (per 2-batch chunk) ----------------
__global__ __launch_bounds__(256) void attn_kernel(const unsigned short* __restrict__ qkv2,
        const unsigned short* __restrict__ Vt, unsigned short* __restrict__ attnb) {
    __shared__ __align__(16) unsigned short Qs[4096];
    __shared__ __align__(16) unsigned short Ks[4096];
    __shared__ __align__(16) unsigned short Vts[4096];
    __shared__ __align__(16) unsigned short Ps[4096];
    int qt = blockIdx.x, h = blockIdx.y, bc = blockIdx.z;
    int tid = threadIdx.x;
    int lane = tid & 63, w = tid >> 6;
    int l15 = lane & 15, quad = lane >> 4;

    // stage Q tile (row = q-row, col = d), swizzled
    const unsigned short* qg = qkv2 + (size_t)(bc * S_DIM + qt * 64) * 3072 + h * 64;
    #pragma unroll
    for (int i = 0; i < 2; i++) {
        int slot = i * 256 + tid;
        int row = slot >> 3, c8 = (slot & 7) ^ (row & 7);
        stage16(qg + (size_t)row * 3072 + c8 * 8, Qs + slot * 8);
    }
    const unsigned short* kg = qkv2 + (size_t)(bc * S_DIM) * 3072 + 1024 + h * 64;
    const unsigned short* vgp = Vt + (size_t)((bc * 16 + h) * 64) * 1088;

    f32x4 acc_o[4];
    float mr[4], lr[4];
    #pragma unroll
    for (int r = 0; r < 4; r++) { mr[r] = -1e30f; lr[r] = 0.f; }
    #pragma unroll
    for (int j = 0; j < 4; j++) acc_o[j] = (f32x4){0.f, 0.f, 0.f, 0.f};

    for (int kt = 0; kt < 17; kt++) {
        __syncthreads();   // prev iter's K/Vt/P reads done
        #pragma unroll
        for (int i = 0; i < 2; i++) {
            int slot = i * 256 + tid;
            int row = slot >> 3, c8 = (slot & 7) ^ (row & 7);
            stage16(kg + (size_t)(kt * 64 + row) * 3072 + c8 * 8, Ks + slot * 8);
            stage16(vgp + (size_t)row * 1088 + kt * 64 + c8 * 8, Vts + slot * 8);
        }
        __syncthreads();   // staging visible (vmcnt drained by barrier)

        // ---- S = Q @ K^T (64 q-rows split: wave w owns rows 16w..16w+15) ----
        f32x4 accS[4];
        #pragma unroll
        for (int j = 0; j < 4; j++) accS[j] = (f32x4){0.f, 0.f, 0.f, 0.f};
        short8 qa0 = *(const short8*)(Qs + sl(16 * w + l15, quad));
        short8 qa1 = *(const short8*)(Qs + sl(16 * w + l15, 4 + quad));
        #pragma unroll
        for (int j = 0; j < 4; j++) {
            short8 kb0 = *(const short8*)(Ks + sl(16 * j + l15, quad));
            short8 kb1 = *(const short8*)(Ks + sl(16 * j + l15, 4 + quad));
            accS[j] = __builtin_amdgcn_mfma_f32_16x16x32_bf16(qa0, kb0, accS[j], 0, 0, 0);
            accS[j] = __builtin_amdgcn_mfma_f32_16x16x32_bf16(qa1, kb1, accS[j], 0, 0, 0);
        }
        // ---- mask + online softmax (row = quad*4 + r within wave's 16 rows) ----
        float pr[4][4];
        #pragma unroll
        for (int j = 0; j < 4; j++) {
            if (kt * 64 + 16 * j + l15 >= S_DIM) {
                #pragma unroll
                for (int r = 0; r < 4; r++) accS[j][r] = -1e30f;
            }
        }
        #pragma unroll
        for (int r = 0; r < 4; r++) {
            float tm = fmaxf(fmaxf(accS[0][r], accS[1][r]), fmaxf(accS[2][r], accS[3][r]));
            #pragma unroll
            for (int off = 1; off < 16; off <<= 1)
                tm = fmaxf(tm, __shfl_xor(tm, off, 64));
            float mnew = fmaxf(mr[r], tm);
            float al = __expf(mr[r] - mnew);
            mr[r] = mnew;
            float rs = 0.f;
            #pragma unroll
            for (int j = 0; j < 4; j++) {
                float p = __expf(accS[j][r] - mnew);
                pr[j][r] = p;
                rs += p;
            }
            #pragma unroll
            for (int off = 1; off < 16; off <<= 1)
                rs += __shfl_xor(rs, off, 64);
            lr[r] = lr[r] * al + rs;
            #pragma unroll
            for (int j = 0; j < 4; j++) acc_o[j][r] *= al;
        }
        // ---- write P to LDS (own rows; same-wave RAW through DS pipe) ----
        #pragma unroll
        for (int j = 0; j < 4; j++) {
            #pragma unroll
            for (int r = 0; r < 4; r++) {
                int prow = quad * 4 + r;
                int idx = sl(16 * w + prow, 2 * j + (l15 >> 3)) + (l15 & 7);
                Ps[idx] = f2b(pr[j][r]);
            }
        }
        // ---- O += P @ V ----
        short8 pa0 = *(const short8*)(Ps + sl(16 * w + l15, quad));
        short8 pa1 = *(const short8*)(Ps + sl(16 * w + l15, 4 + quad));
        #pragma unroll
        for (int j = 0; j < 4; j++) {
            short8 vb0 = *(const short8*)(Vts + sl(16 * j + l15, quad));
            short8 vb1 = *(const short8*)(Vts + sl(16 * j + l15, 4 + quad));
            acc_o[j] = __builtin_amdgcn_mfma_f32_16x16x32_bf16(pa0, vb0, acc_o[j], 0, 0, 0);
            acc_o[j] = __builtin_amdgcn_mfma_f32_16x16x32_bf16(pa1, vb1, acc_o[j], 0, 0, 0);
        }
    }
    // ---- epilogue ----
    #pragma unroll
    for (int r = 0; r < 4; r++) {
        int s = qt * 64 + 16 * w + quad * 4 + r;
        if (s >= S_DIM) continue;
        float invl = 1.0f / lr[r];
        #pragma unroll
        for (int j = 0; j < 4; j++)
            attnb[(size_t)(bc * S_DIM + s) * E_DIM + h * 64 + 16 * j + l15] =
                f2b(acc_o[j][r] * invl);
    }
}

// ---------------- depthwise 3x3 conv + exact GELU + gate (per-batch, bf16) ----------------
__global__ __launch_bounds__(256) void conv_gelu_kernel(const unsigned short* __restrict__ hb,
        const float* __restrict__ dw_w, const float* __restrict__ dw_b,
        unsigned short* __restrict__ act) {
    int p = blockIdx.x;
    for (int c = threadIdx.x; c < KP_FC2; c += 256) {
        if (c >= HID_DIM) { act[(size_t)p * KP_FC2 + c] = 0; continue; }
        float val;
        if (p == 0) {
            val = b2f(hb[(size_t)p * 5460 + c]);
        } else {
            int pp = p - 1;
            int gy = pp >> 5, gx = pp & 31;
            float a = dw_b[c];
            #pragma unroll
            for (int dy = 0; dy < 3; dy++) {
                int ny = gy + dy - 1;
                if (ny < 0 || ny >= 32) continue;
                #pragma unroll
                for (int dx = 0; dx < 3; dx++) {
                    int nx = gx + dx - 1;
                    if (nx < 0 || nx >= 32) continue;
                    a = fmaf(b2f(hb[(size_t)(1 + ny * 32 + nx) * 5460 + c]),
                             dw_w[(dy * 3 + dx) * HID_DIM + c], a);
                }
            }
            val = a;
        }
        float ge = 0.5f * val * (1.0f + erff(val * 0.70710678118654752f));
        act[(size_t)p * KP_FC2 + c] = f2b(ge * b2f(hb[(size_t)p * 5460 + HID_DIM + c]));
    }
}

// ---------------- launch ----------------
extern "C" void kernel_launch(void* const* d_in, const int* in_sizes, int n_in,
                              void* d_out, int out_size, void* d_ws, size_t ws_size,
                              hipStream_t stream) {
    const float* x      = (const float*)d_in[0];
    const float* g1     = (const float*)d_in[1];
    const float* w_qkv  = (const float*)d_in[2];
    const float* b_qkv  = (const float*)d_in[3];
    const float* w_proj = (const float*)d_in[4];
    const float* b_proj = (const float*)d_in[5];
    const float* g2     = (const float*)d_in[6];
    const float* fc1_w  = (const float*)d_in[7];
    const float* fc1_b  = (const float*)d_in[8];
    const float* dw_w   = (const float*)d_in[9];
    const float* dw_b   = (const float*)d_in[10];
    const float* fc2_w  = (const float*)d_in[11];
    const float* fc2_b  = (const float*)d_in[12];
    float* out = (float*)d_out;
    char* base = (char*)d_ws;

    // ws arena (bytes), peak 43.6 MB (< proven-safe 56 MB)
    unsigned short* xnc   = (unsigned short*)(base + 0);          // 2176x1024 bf16 (phase1 chunk xn; phase2 per-batch xn)
    unsigned short* qkv2  = (unsigned short*)(base + 4456448);    // 2176x3072 bf16 (phase1)
    unsigned short* Vt2   = (unsigned short*)(base + 17825792);   // 2x16x64x1088 bf16 (phase1)
    unsigned short* attnb = (unsigned short*)(base + 22282240);   // 2176x1024 bf16 (phase1)
    unsigned short* qkvT  = (unsigned short*)(base + 26738688);   // 3072x1024 bf16 (phase1)
    unsigned short* projT = (unsigned short*)(base + 33030144);   // 1024x1024 bf16 (phase1)
    unsigned short* hbufb = (unsigned short*)(base + 4456448);    // 1152x5460 bf16 (phase2, reuses qkv2)
    unsigned short* actb  = (unsigned short*)(base + 17825792);   // 1152x2752 bf16 (phase2, reuses Vt2/attnb)
    unsigned short* fc1T  = (unsigned short*)(base + 26738688);   // 5504x1024 bf16 (phase2, reuses qkvT/projT)
    unsigned short* fc2T  = (unsigned short*)(base + 38010880);   // 1024x2752 bf16 (phase2)

    // ---- attention phase: weights, then 4 chunks of 2 batches ----
    convt_kernel<<<dim3(96, 32), 256, 0, stream>>>(w_qkv, qkvT, 1024, 3072, 1024);
    convt_kernel<<<dim3(32, 32), 256, 0, stream>>>(w_proj, projT, 1024, 1024, 1024);
    for (int c = 0; c < 4; c++) {
        size_t roff = (size_t)c * 2 * S_DIM;
        rmsnorm_kernel<<<2 * S_DIM, 256, 0, stream>>>(x + roff * E_DIM, g1, xnc);
        gemm_mfma<true><<<dim3(24, 17), 256, 0, stream>>>(xnc, qkvT, b_qkv, nullptr,
                qkv2, 2 * S_DIM, 3072, 1024, 3072);
        rope_kernel<<<4100, 256, 0, stream>>>(qkv2);
        vtrans_kernel<<<dim3(17, 16, 2), 256, 0, stream>>>(qkv2, Vt2);
        attn_kernel<<<dim3(17, 16, 2), 256, 0, stream>>>(qkv2, Vt2, attnb);
        gemm_mfma<false><<<dim3(8, 17), 256, 0, stream>>>(attnb, projT, b_proj,
                x + roff * E_DIM, out + roff * E_DIM, 2 * S_DIM, 1024, 1024, 1024);
    }

    // ---- MLP phase: weights, then per-batch ----
    convt_kernel<<<dim3(171, 32), 256, 0, stream>>>(fc1_w, fc1T, 1024, 5460, 1024);
    convt_kernel<<<dim3(32, 86), 256, 0, stream>>>(fc2_w, fc2T, HID_DIM, 1024, KP_FC2);
    for (int b = 0; b < B_DIM; b++) {
        float* outb = out + (size_t)b * S_DIM * E_DIM;
        rmsnorm_kernel<<<S_DIM, 256, 0, stream>>>(outb, g2, xnc);
        gemm_mfma<true><<<dim3(43, 9), 256, 0, stream>>>(xnc, fc1T, fc1_b, nullptr,
                hbufb, S_DIM, 5460, 1024, 5460);
        conv_gelu_kernel<<<S_DIM, 256, 0, stream>>>(hbufb, dw_w, dw_b, actb);
        gemm_mfma<false><<<dim3(8, 9), 256, 0, stream>>>(actb, fc2T, fc2_b, outb,
                outb, S_DIM, 1024, KP_FC2, 1024);
    }
}

// Round 5
// 1454.812 us; speedup vs baseline: 4.5553x; 1.5070x over previous
//
#include <hip/hip_runtime.h>
#include <hip/hip_bf16.h>
#include <math.h>

#define E_DIM 1024
#define NHEAD 16
#define HID_DIM 2730
#define KP_FC2 2752
#define B_DIM 8
#define S_DIM 1025
#define EPS_V 1e-6f
#define SCALE_V 0.125f
#define MROWS (B_DIM * S_DIM)   // 8200

typedef __attribute__((ext_vector_type(8))) short short8;
typedef __attribute__((ext_vector_type(4))) float f32x4;

__device__ __forceinline__ float b2f(unsigned short u) {
    union { unsigned int i; float f; } x; x.i = ((unsigned int)u) << 16; return x.f;
}
__device__ __forceinline__ unsigned short f2b(float f) {
    __hip_bfloat16 h = __float2bfloat16(f);
    return *reinterpret_cast<unsigned short*>(&h);
}

__device__ __forceinline__ void stage16(const void* g, void* l) {
    __builtin_amdgcn_global_load_lds(
        (const __attribute__((address_space(1))) unsigned int*)g,
        (__attribute__((address_space(3))) unsigned int*)l,
        16, 0, 0);
}

// u16 index of the 8-element group at (row, c8) in a XOR-swizzled [64][64] bf16 tile
__device__ __forceinline__ int sl(int row, int c8) {
    return (row * 8 + (c8 ^ (row & 7))) * 8;
}

// ---------------- RMSNorm (fp32 in -> bf16 out) ----------------
__global__ __launch_bounds__(256) void rmsnorm_kernel(const float* __restrict__ x,
        const float* __restrict__ g, unsigned short* __restrict__ out) {
    int row = blockIdx.x;
    const float4* xr = (const float4*)(x + (size_t)row * E_DIM);
    float4 v = xr[threadIdx.x];
    float ss = v.x*v.x + v.y*v.y + v.z*v.z + v.w*v.w;
    #pragma unroll
    for (int off = 32; off > 0; off >>= 1) ss += __shfl_down(ss, off, 64);
    __shared__ float wsum[4];
    int lane = threadIdx.x & 63, w = threadIdx.x >> 6;
    if (lane == 0) wsum[w] = ss;
    __syncthreads();
    float tot = wsum[0] + wsum[1] + wsum[2] + wsum[3];
    float inv = rsqrtf(tot * (1.0f / E_DIM) + EPS_V);
    float4 gv = ((const float4*)g)[threadIdx.x];
    ushort4 o;
    o.x = f2b(v.x * inv * gv.x); o.y = f2b(v.y * inv * gv.y);
    o.z = f2b(v.z * inv * gv.z); o.w = f2b(v.w * inv * gv.w);
    ((ushort4*)(out + (size_t)row * E_DIM))[threadIdx.x] = o;
}

// ---------------- weight convert+transpose: W[K][N] f32 -> WT[n][k] bf16 ----------------
__global__ __launch_bounds__(256) void convt_kernel(const float* __restrict__ W,
        unsigned short* __restrict__ WT, int K, int N, int KPad) {
    __shared__ float T[32][33];
    int n0 = blockIdx.x * 32, k0 = blockIdx.y * 32;
    int c = threadIdx.x & 31, r4 = (threadIdx.x >> 5) << 2;
    #pragma unroll
    for (int i = 0; i < 4; i++) {
        int k = k0 + r4 + i, n = n0 + c;
        T[c][r4 + i] = (k < K && n < N) ? W[(size_t)k * N + n] : 0.0f;
    }
    __syncthreads();
    #pragma unroll
    for (int i = 0; i < 4; i++) {
        int n = n0 + r4 + i, k = k0 + c;
        if (n < N && k < KPad) WT[(size_t)n * KPad + k] = f2b(T[r4 + i][c]);
    }
}

// ---------------- bf16 MFMA GEMM, double-buffered LDS staging ----------------
// A: [M][K] bf16, Bt: [N][K] bf16, K % 32 == 0; A/Bt physically padded to 128-row tiles.
template<bool BF16OUT>
__global__ __launch_bounds__(256) void gemm_mfma(const unsigned short* __restrict__ A,
        const unsigned short* __restrict__ Bt, const float* __restrict__ bias,
        const float* __restrict__ R, void* __restrict__ Cv,
        int M, int N, int K, int ldc) {
    __shared__ __align__(16) unsigned short ldsA[2][4096];
    __shared__ __align__(16) unsigned short ldsB[2][4096];
    int tid = threadIdx.x;
    int lane = tid & 63;
    int w = tid >> 6;
    int wm = w >> 1, wn = w & 1;
    int m0 = blockIdx.y * 128, n0 = blockIdx.x * 128;

    int c0 = 2 * w, c1 = 2 * w + 1;
    int kc0 = c0 & 3, rh0 = (c0 >> 2) * 64;
    int kc1 = c1 & 3, rh1 = (c1 >> 2) * 64;
    const unsigned short* gA0 = A + (size_t)(m0 + rh0 + lane) * K + kc0 * 8;
    const unsigned short* gA1 = A + (size_t)(m0 + rh1 + lane) * K + kc1 * 8;
    const unsigned short* gB0 = Bt + (size_t)(n0 + rh0 + lane) * K + kc0 * 8;
    const unsigned short* gB1 = Bt + (size_t)(n0 + rh1 + lane) * K + kc1 * 8;
    unsigned int off0 = (kc0 * 128 + rh0) * 8;   // wave-uniform LDS base (HW adds lane*16B)
    unsigned int off1 = (kc1 * 128 + rh1) * 8;
    unsigned int offPa = ((lane >> 4) * 128 + wm * 64 + (lane & 15)) * 8;
    unsigned int offPb = ((lane >> 4) * 128 + wn * 64 + (lane & 15)) * 8;

    f32x4 acc[4][4];
    #pragma unroll
    for (int i = 0; i < 4; i++)
        #pragma unroll
        for (int j = 0; j < 4; j++) acc[i][j] = (f32x4){0.f, 0.f, 0.f, 0.f};

    int nk = K >> 5;
    // prologue: stage tile 0 into buffer 0
    stage16(gA0, &ldsA[0][off0]);
    stage16(gA1, &ldsA[0][off1]);
    stage16(gB0, &ldsB[0][off0]);
    stage16(gB1, &ldsB[0][off1]);

    for (int t = 0; t < nk; t++) {
        int cur = t & 1, nxt = cur ^ 1;
        __syncthreads();                 // drains own vmcnt -> buf[cur] ready; prev reads of buf[nxt] done
        if (t + 1 < nk) {                // prefetch next tile (waited at NEXT barrier)
            int k0 = (t + 1) << 5;
            stage16(gA0 + k0, &ldsA[nxt][off0]);
            stage16(gA1 + k0, &ldsA[nxt][off1]);
            stage16(gB0 + k0, &ldsB[nxt][off0]);
            stage16(gB1 + k0, &ldsB[nxt][off1]);
        }
        const unsigned short* pa = &ldsA[cur][offPa];
        const unsigned short* pb = &ldsB[cur][offPb];
        short8 af[4], bfr[4];
        #pragma unroll
        for (int i = 0; i < 4; i++) af[i] = *(const short8*)(pa + i * 128);
        #pragma unroll
        for (int j = 0; j < 4; j++) bfr[j] = *(const short8*)(pb + j * 128);
        #pragma unroll
        for (int i = 0; i < 4; i++)
            #pragma unroll
            for (int j = 0; j < 4; j++)
                acc[i][j] = __builtin_amdgcn_mfma_f32_16x16x32_bf16(af[i], bfr[j], acc[i][j], 0, 0, 0);
    }

    int cr = (lane >> 4) * 4;
    int cc = lane & 15;
    #pragma unroll
    for (int i = 0; i < 4; i++) {
        int gmb = m0 + wm * 64 + i * 16 + cr;
        #pragma unroll
        for (int j = 0; j < 4; j++) {
            int gn = n0 + wn * 64 + j * 16 + cc;
            if (gn >= N) continue;
            float bs = bias[gn];
            #pragma unroll
            for (int r = 0; r < 4; r++) {
                int gm = gmb + r;
                if (gm >= M) continue;
                float v = acc[i][j][r] + bs;
                if (BF16OUT) {
                    ((unsigned short*)Cv)[(size_t)gm * ldc + gn] = f2b(v);
                } else {
                    ((float*)Cv)[(size_t)gm * ldc + gn] = v + R[(size_t)gm * ldc + gn];
                }
            }
        }
    }
}

// ---------------- RoPE (per 2-batch chunk, in-place, rows 0..2049) ----------------
__global__ __launch_bounds__(256) void rope_kernel(unsigned short* __restrict__ qkv2) {
    int idx = blockIdx.x * 256 + threadIdx.x;
    int i = idx & 31;
    int h = (idx >> 5) & (NHEAD - 1);
    int rc = idx >> 9;
    int s = (rc < S_DIM) ? rc : rc - S_DIM;
    unsigned short* q = qkv2 + (size_t)rc * 3072 + h * 64;
    unsigned short* k = q + 1024;
    if (s == 0) {
        q[i] = f2b(b2f(q[i]) * SCALE_V);
        q[i + 32] = f2b(b2f(q[i + 32]) * SCALE_V);
        return;
    }
    float pos = (float)(s - 1);
    float invf = expf((float)i * (-9.210340371976184f / 32.0f));
    float f = pos * invf;
    float c = cosf(f), sn = sinf(f);
    float q1 = b2f(q[i]), q2 = b2f(q[i + 32]);
    q[i]      = f2b((q1 * c - q2 * sn) * SCALE_V);
    q[i + 32] = f2b((q2 * c + q1 * sn) * SCALE_V);
    float k1 = b2f(k[i]), k2 = b2f(k[i + 32]);
    k[i]      = f2b(k1 * c - k2 * sn);
    k[i + 32] = f2b(k2 * c + k1 * sn);
}

// ---------------- V transpose: qkv2 v-section -> Vt[bc][h][d][1088] ----------------
__global__ __launch_bounds__(256) void vtrans_kernel(const unsigned short* __restrict__ qkv2,
        unsigned short* __restrict__ Vt) {
    __shared__ unsigned short T[64][65];
    int st = blockIdx.x, h = blockIdx.y, bc = blockIdx.z;
    int tid = threadIdx.x;
    int r = tid & 63, cb = (tid >> 6) * 16;
    const unsigned short* src = qkv2 + (size_t)(bc * S_DIM + st * 64 + r) * 3072 + 2048 + h * 64 + cb;
    #pragma unroll
    for (int i = 0; i < 4; i++) {
        ushort4 v = *(const ushort4*)(src + i * 4);
        T[cb + i*4 + 0][r] = v.x; T[cb + i*4 + 1][r] = v.y;
        T[cb + i*4 + 2][r] = v.z; T[cb + i*4 + 3][r] = v.w;
    }
    __syncthreads();
    int d = tid >> 2, sc = (tid & 3) * 16;
    unsigned short* dst = Vt + ((size_t)((bc * 16 + h) * 64 + d)) * 1088 + st * 64 + sc;
    #pragma unroll
    for (int g = 0; g < 4; g++) {
        ushort4 o;
        int i0 = sc + g * 4;
        o.x = (st*64 + i0 + 0 < S_DIM) ? T[d][i0 + 0] : 0;
        o.y = (st*64 + i0 + 1 < S_DIM) ? T[d][i0 + 1] : 0;
        o.z = (st*64 + i0 + 2 < S_DIM) ? T[d][i0 + 2] : 0;
        o.w = (st*64 + i0 + 3 < S_DIM) ? T[d][i0 + 3] : 0;
        *(ushort4*)(dst + g * 4) = o;
    }
}

// ---------------- MFMA flash attention (per 2-batch chunk) ----------------
__global__ __launch_bounds__(256) void attn_kernel(const unsigned short* __restrict__ qkv2,
        const unsigned short* __restrict__ Vt, unsigned short* __restrict__ attnb) {
    __shared__ __align__(16) unsigned short Qs[4096];
    __shared__ __align__(16) unsigned short Ks[4096];
    __shared__ __align__(16) unsigned short Vts[4096];
    __shared__ __align__(16) unsigned short Ps[4096];
    int qt = blockIdx.x, h = blockIdx.y, bc = blockIdx.z;
    int tid = threadIdx.x;
    int lane = tid & 63, w = tid >> 6;
    int l15 = lane & 15, quad = lane >> 4;

    const unsigned short* qg = qkv2 + (size_t)(bc * S_DIM + qt * 64) * 3072 + h * 64;
    #pragma unroll
    for (int i = 0; i < 2; i++) {
        int slot = i * 256 + tid;
        int row = slot >> 3, c8 = (slot & 7) ^ (row & 7);
        stage16(qg + (size_t)row * 3072 + c8 * 8, Qs + slot * 8);
    }
    const unsigned short* kg = qkv2 + (size_t)(bc * S_DIM) * 3072 + 1024 + h * 64;
    const unsigned short* vgp = Vt + (size_t)((bc * 16 + h) * 64) * 1088;

    f32x4 acc_o[4];
    float mr[4], lr[4];
    #pragma unroll
    for (int r = 0; r < 4; r++) { mr[r] = -1e30f; lr[r] = 0.f; }
    #pragma unroll
    for (int j = 0; j < 4; j++) acc_o[j] = (f32x4){0.f, 0.f, 0.f, 0.f};

    for (int kt = 0; kt < 17; kt++) {
        __syncthreads();
        #pragma unroll
        for (int i = 0; i < 2; i++) {
            int slot = i * 256 + tid;
            int row = slot >> 3, c8 = (slot & 7) ^ (row & 7);
            stage16(kg + (size_t)(kt * 64 + row) * 3072 + c8 * 8, Ks + slot * 8);
            stage16(vgp + (size_t)row * 1088 + kt * 64 + c8 * 8, Vts + slot * 8);
        }
        __syncthreads();

        f32x4 accS[4];
        #pragma unroll
        for (int j = 0; j < 4; j++) accS[j] = (f32x4){0.f, 0.f, 0.f, 0.f};
        short8 qa0 = *(const short8*)(Qs + sl(16 * w + l15, quad));
        short8 qa1 = *(const short8*)(Qs + sl(16 * w + l15, 4 + quad));
        #pragma unroll
        for (int j = 0; j < 4; j++) {
            short8 kb0 = *(const short8*)(Ks + sl(16 * j + l15, quad));
            short8 kb1 = *(const short8*)(Ks + sl(16 * j + l15, 4 + quad));
            accS[j] = __builtin_amdgcn_mfma_f32_16x16x32_bf16(qa0, kb0, accS[j], 0, 0, 0);
            accS[j] = __builtin_amdgcn_mfma_f32_16x16x32_bf16(qa1, kb1, accS[j], 0, 0, 0);
        }
        float pr[4][4];
        #pragma unroll
        for (int j = 0; j < 4; j++) {
            if (kt * 64 + 16 * j + l15 >= S_DIM) {
                #pragma unroll
                for (int r = 0; r < 4; r++) accS[j][r] = -1e30f;
            }
        }
        #pragma unroll
        for (int r = 0; r < 4; r++) {
            float tm = fmaxf(fmaxf(accS[0][r], accS[1][r]), fmaxf(accS[2][r], accS[3][r]));
            #pragma unroll
            for (int off = 1; off < 16; off <<= 1)
                tm = fmaxf(tm, __shfl_xor(tm, off, 64));
            float mnew = fmaxf(mr[r], tm);
            float al = __expf(mr[r] - mnew);
            mr[r] = mnew;
            float rs = 0.f;
            #pragma unroll
            for (int j = 0; j < 4; j++) {
                float p = __expf(accS[j][r] - mnew);
                pr[j][r] = p;
                rs += p;
            }
            #pragma unroll
            for (int off = 1; off < 16; off <<= 1)
                rs += __shfl_xor(rs, off, 64);
            lr[r] = lr[r] * al + rs;
            #pragma unroll
            for (int j = 0; j < 4; j++) acc_o[j][r] *= al;
        }
        #pragma unroll
        for (int j = 0; j < 4; j++) {
            #pragma unroll
            for (int r = 0; r < 4; r++) {
                int prow = quad * 4 + r;
                int idx = sl(16 * w + prow, 2 * j + (l15 >> 3)) + (l15 & 7);
                Ps[idx] = f2b(pr[j][r]);
            }
        }
        short8 pa0 = *(const short8*)(Ps + sl(16 * w + l15, quad));
        short8 pa1 = *(const short8*)(Ps + sl(16 * w + l15, 4 + quad));
        #pragma unroll
        for (int j = 0; j < 4; j++) {
            short8 vb0 = *(const short8*)(Vts + sl(16 * j + l15, quad));
            short8 vb1 = *(const short8*)(Vts + sl(16 * j + l15, 4 + quad));
            acc_o[j] = __builtin_amdgcn_mfma_f32_16x16x32_bf16(pa0, vb0, acc_o[j], 0, 0, 0);
            acc_o[j] = __builtin_amdgcn_mfma_f32_16x16x32_bf16(pa1, vb1, acc_o[j], 0, 0, 0);
        }
    }
    #pragma unroll
    for (int r = 0; r < 4; r++) {
        int s = qt * 64 + 16 * w + quad * 4 + r;
        if (s >= S_DIM) continue;
        float invl = 1.0f / lr[r];
        #pragma unroll
        for (int j = 0; j < 4; j++)
            attnb[(size_t)(bc * S_DIM + s) * E_DIM + h * 64 + 16 * j + l15] =
                f2b(acc_o[j][r] * invl);
    }
}

// ---------------- depthwise 3x3 conv + exact GELU + gate (2-batch chunk) ----------------
__global__ __launch_bounds__(256) void conv_gelu_kernel(const unsigned short* __restrict__ hb,
        const float* __restrict__ dw_w, const float* __restrict__ dw_b,
        unsigned short* __restrict__ act) {
    int p = blockIdx.x % S_DIM;
    size_t row = blockIdx.x;
    size_t brow = row - p;      // batch base row
    for (int c = threadIdx.x; c < KP_FC2; c += 256) {
        if (c >= HID_DIM) { act[row * KP_FC2 + c] = 0; continue; }
        float val;
        if (p == 0) {
            val = b2f(hb[row * 5460 + c]);
        } else {
            int pp = p - 1;
            int gy = pp >> 5, gx = pp & 31;
            float a = dw_b[c];
            #pragma unroll
            for (int dy = 0; dy < 3; dy++) {
                int ny = gy + dy - 1;
                if (ny < 0 || ny >= 32) continue;
                #pragma unroll
                for (int dx = 0; dx < 3; dx++) {
                    int nx = gx + dx - 1;
                    if (nx < 0 || nx >= 32) continue;
                    a = fmaf(b2f(hb[(brow + 1 + ny * 32 + nx) * 5460 + c]),
                             dw_w[(dy * 3 + dx) * HID_DIM + c], a);
                }
            }
            val = a;
        }
        float ge = 0.5f * val * (1.0f + erff(val * 0.70710678118654752f));
        act[row * KP_FC2 + c] = f2b(ge * b2f(hb[row * 5460 + HID_DIM + c]));
    }
}

// ---------------- launch ----------------
extern "C" void kernel_launch(void* const* d_in, const int* in_sizes, int n_in,
                              void* d_out, int out_size, void* d_ws, size_t ws_size,
                              hipStream_t stream) {
    const float* x      = (const float*)d_in[0];
    const float* g1     = (const float*)d_in[1];
    const float* w_qkv  = (const float*)d_in[2];
    const float* b_qkv  = (const float*)d_in[3];
    const float* w_proj = (const float*)d_in[4];
    const float* b_proj = (const float*)d_in[5];
    const float* g2     = (const float*)d_in[6];
    const float* fc1_w  = (const float*)d_in[7];
    const float* fc1_b  = (const float*)d_in[8];
    const float* dw_w   = (const float*)d_in[9];
    const float* dw_b   = (const float*)d_in[10];
    const float* fc2_w  = (const float*)d_in[11];
    const float* fc2_b  = (const float*)d_in[12];
    float* out = (float*)d_out;
    char* base = (char*)d_ws;

    // ---- phase 1 layout (47.7 MB) ----
    unsigned short* xnc   = (unsigned short*)(base + 0);          // 2176 x 1024
    unsigned short* qkv2  = (unsigned short*)(base + 4456448);    // 2176 x 3072
    unsigned short* Vt2   = (unsigned short*)(base + 17825792);   // 2x16x64x1088
    unsigned short* attnb = (unsigned short*)(base + 22282240);   // 8320 x 1024 (FULL)
    unsigned short* qkvT  = (unsigned short*)(base + 39321600);   // 3072 x 1024
    unsigned short* projT = (unsigned short*)(base + 45613056);   // 1024 x 1024  (end 47,710,208)
    // ---- phase 2 layout (55.7 MB) ----
    unsigned short* hbufb = (unsigned short*)(base + 4456448);    // 2050 x 5460  (end 26,842,448)
    unsigned short* actb  = (unsigned short*)(base + 26842624);   // 2176 x 2752  (end 38,819,328)
    unsigned short* fc1T  = (unsigned short*)(base + 38819328);   // 5504 x 1024  (end 50,091,520)
    unsigned short* fc2T  = (unsigned short*)(base + 50091520);   // 1024 x 2752  (end 55,727,616)

    // ---- attention phase ----
    convt_kernel<<<dim3(96, 32), 256, 0, stream>>>(w_qkv, qkvT, 1024, 3072, 1024);
    convt_kernel<<<dim3(32, 32), 256, 0, stream>>>(w_proj, projT, 1024, 1024, 1024);
    for (int c = 0; c < 4; c++) {
        size_t roff = (size_t)c * 2 * S_DIM;
        rmsnorm_kernel<<<2 * S_DIM, 256, 0, stream>>>(x + roff * E_DIM, g1, xnc);
        gemm_mfma<true><<<dim3(24, 17), 256, 0, stream>>>(xnc, qkvT, b_qkv, nullptr,
                qkv2, 2 * S_DIM, 3072, 1024, 3072);
        rope_kernel<<<4100, 256, 0, stream>>>(qkv2);
        vtrans_kernel<<<dim3(17, 16, 2), 256, 0, stream>>>(qkv2, Vt2);
        attn_kernel<<<dim3(17, 16, 2), 256, 0, stream>>>(qkv2, Vt2,
                attnb + roff * E_DIM);
    }
    // proj over ALL rows in one dispatch (520 blocks)
    gemm_mfma<false><<<dim3(8, 65), 256, 0, stream>>>(attnb, projT, b_proj,
            x, out, MROWS, 1024, 1024, 1024);

    // ---- MLP phase ----
    convt_kernel<<<dim3(171, 32), 256, 0, stream>>>(fc1_w, fc1T, 1024, 5460, 1024);
    convt_kernel<<<dim3(32, 86), 256, 0, stream>>>(fc2_w, fc2T, HID_DIM, 1024, KP_FC2);
    for (int c = 0; c < 4; c++) {
        size_t roff = (size_t)c * 2 * S_DIM;
        float* outc = out + roff * E_DIM;
        rmsnorm_kernel<<<2 * S_DIM, 256, 0, stream>>>(outc, g2, xnc);
        gemm_mfma<true><<<dim3(43, 17), 256, 0, stream>>>(xnc, fc1T, fc1_b, nullptr,
                hbufb, 2 * S_DIM, 5460, 1024, 5460);
        conv_gelu_kernel<<<2 * S_DIM, 256, 0, stream>>>(hbufb, dw_w, dw_b, actb);
        gemm_mfma<false><<<dim3(8, 17), 256, 0, stream>>>(actb, fc2T, fc2_b, outc,
                outc, 2 * S_DIM, 1024, KP_FC2, 1024);
    }
}